// Round 2
// baseline (651.942 us; speedup 1.0000x reference)
//
#include <hip/hip_runtime.h>

// LSALayer fused: windowed (4x4 patch, 16-token) self-attention, C=256.
// I/O is float32 (reference dtypes). Internally: bf16 MFMA, f32 accum.
// Pre-kernel converts Wq/Wo -> bf16 in d_ws; main kernel reads B-frags
// straight from L2 (no cross-wave LDS staging, no barriers).

typedef __attribute__((ext_vector_type(8))) short short8;   // 8 bf16
typedef __attribute__((ext_vector_type(4))) float floatx4;  // MFMA C/D

static __device__ inline short f2bf(float f) {
    unsigned u = __float_as_uint(f);
    u = (u + 0x7FFFu + ((u >> 16) & 1u)) >> 16;  // RNE
    return (short)u;
}
static __device__ inline short8 zero8() {
    short8 v;
#pragma unroll
    for (int k = 0; k < 8; ++k) v[k] = 0;
    return v;
}
static __device__ inline floatx4 zf4() {
    floatx4 v;
#pragma unroll
    for (int k = 0; k < 4; ++k) v[k] = 0.0f;
    return v;
}

__global__ void convert_weights(const float* __restrict__ Wq,
                                const float* __restrict__ Wo,
                                short* __restrict__ wbf) {
    int idx = blockIdx.x * 256 + threadIdx.x;  // 0..32767
#pragma unroll
    for (int i = 0; i < 2; ++i) {
        int j = idx + i * 32768;               // 0..65535
        wbf[j]         = f2bf(Wq[j]);
        wbf[65536 + j] = f2bf(Wo[j]);
    }
}

// Block = 256 threads = 4 waves; each wave owns TWO windows (shared B-frags).
// Grid = 2048 blocks -> 16384 windows. All LDS is wave-private: no barriers.
__global__ __launch_bounds__(256, 2) void lsa_fused(
    const float* __restrict__ x, const short* __restrict__ wbf,
    const float* __restrict__ bq, const float* __restrict__ bo,
    float* __restrict__ out) {
    __shared__ __align__(16) short Qrm[4][2][16 * 264];  // 67584 B (row pad +8)
    __shared__ __align__(16) short Pl[4][2][16 * 24];    //  6144 B

    const int tid  = threadIdx.x;
    const int wv   = tid >> 6;
    const int lane = tid & 63;
    const int l15  = lane & 15;
    const int quad = lane >> 4;

    const int wid0 = (blockIdx.x * 4 + wv) * 2;
    const int pi = l15 >> 2, pj = l15 & 3;     // token l15 -> pixel in 4x4 patch

    const float* xrow[2];
#pragma unroll
    for (int w = 0; w < 2; ++w) {
        int wid = wid0 + w;
        int b = wid >> 12, hp = (wid >> 6) & 63, wp = wid & 63;
        xrow[w] = x + ((size_t)b << 24) + ((size_t)((hp << 2) + pi) << 16)
                    + ((size_t)((wp << 2) + pj) << 8);
    }

    floatx4 acc[2][16];
#pragma unroll
    for (int w = 0; w < 2; ++w)
#pragma unroll
        for (int nt = 0; nt < 16; ++nt) acc[w][nt] = zf4();

    // ------------- GEMM1: Q = X @ Wq^T  (per window M=16, N=256, K=256) -------------
    for (int kk = 0; kk < 8; ++kk) {
        short8 af[2];
#pragma unroll
        for (int w = 0; w < 2; ++w) {
            const float* p = xrow[w] + kk * 32 + quad * 8;
            float4 v0 = *(const float4*)p;
            float4 v1 = *(const float4*)(p + 4);
            short8 a;
            a[0] = f2bf(v0.x); a[1] = f2bf(v0.y); a[2] = f2bf(v0.z); a[3] = f2bf(v0.w);
            a[4] = f2bf(v1.x); a[5] = f2bf(v1.y); a[6] = f2bf(v1.z); a[7] = f2bf(v1.w);
            af[w] = a;
        }
#pragma unroll
        for (int nt = 0; nt < 16; ++nt) {
            // B-frag: lane holds Wq[n = nt*16+l15][k = kk*32+quad*8 ..+8] (bf16, from L2)
            short8 bfr = *(const short8*)(wbf + (nt * 16 + l15) * 256 + kk * 32 + quad * 8);
            acc[0][nt] = __builtin_amdgcn_mfma_f32_16x16x32_bf16(af[0], bfr, acc[0][nt], 0, 0, 0);
            acc[1][nt] = __builtin_amdgcn_mfma_f32_16x16x32_bf16(af[1], bfr, acc[1][nt], 0, 0, 0);
        }
    }

    // bias + write Q to wave-private LDS row-major (C-layout: row=quad*4+r, col=l15)
#pragma unroll
    for (int nt = 0; nt < 16; ++nt) {
        float bqv = bq[nt * 16 + l15];
#pragma unroll
        for (int w = 0; w < 2; ++w) {
            short* q = &Qrm[wv][w][0];
#pragma unroll
            for (int r = 0; r < 4; ++r)
                q[(quad * 4 + r) * 264 + nt * 16 + l15] = f2bf(acc[w][nt][r] + bqv);
        }
    }

    // ------------- attention per window: S = QQ^T, softmax, Z = PQ -------------
#pragma unroll 1
    for (int w = 0; w < 2; ++w) {
        short* q  = &Qrm[wv][w][0];
        short* pl = &Pl[wv][w][0];

        floatx4 s = zf4();
#pragma unroll
        for (int kk = 0; kk < 8; ++kk) {
            // A-frag == B-frag for Q Q^T: lane holds Q[l15][kk*32+quad*8 ..+8]
            short8 qf = *(const short8*)&q[l15 * 264 + kk * 32 + quad * 8];
            s = __builtin_amdgcn_mfma_f32_16x16x32_bf16(qf, qf, s, 0, 0, 0);
        }
        floatx4 p;
#pragma unroll
        for (int r = 0; r < 4; ++r) {
            float v = s[r];
            float m = v;
#pragma unroll
            for (int d = 1; d < 16; d <<= 1) m = fmaxf(m, __shfl_xor(m, d, 64));
            float e = __expf(v - m);
            float sum = e;
#pragma unroll
            for (int d = 1; d < 16; d <<= 1) sum += __shfl_xor(sum, d, 64);
            p[r] = e / sum;
        }
#pragma unroll
        for (int r = 0; r < 4; ++r)
            pl[(quad * 4 + r) * 24 + l15] = f2bf(p[r]);

        // Z = P @ Q (K=16 zero-padded to 32); compute ALL tiles, then overwrite Q
        short8 pf = zero8();
        if (quad < 2) pf = *(const short8*)&pl[l15 * 24 + quad * 8];
        floatx4 z[16];
#pragma unroll
        for (int nt = 0; nt < 16; ++nt) {
            short8 qb = zero8();
            if (quad < 2) {
#pragma unroll
                for (int jj = 0; jj < 8; ++jj)
                    qb[jj] = q[(quad * 8 + jj) * 264 + nt * 16 + l15];
            }
            z[nt] = __builtin_amdgcn_mfma_f32_16x16x32_bf16(pf, qb, zf4(), 0, 0, 0);
        }
#pragma unroll
        for (int nt = 0; nt < 16; ++nt)
#pragma unroll
            for (int r = 0; r < 4; ++r)
                q[(quad * 4 + r) * 264 + nt * 16 + l15] = f2bf(z[nt][r]);
    }

    // ------------- GEMM2: out = Z @ Wo^T + bo -------------
#pragma unroll
    for (int w = 0; w < 2; ++w)
#pragma unroll
        for (int nt = 0; nt < 16; ++nt) acc[w][nt] = zf4();

    for (int kk = 0; kk < 8; ++kk) {
        short8 zf[2];
#pragma unroll
        for (int w = 0; w < 2; ++w)
            zf[w] = *(const short8*)&Qrm[wv][w][l15 * 264 + kk * 32 + quad * 8];
#pragma unroll
        for (int nt = 0; nt < 16; ++nt) {
            short8 bfr = *(const short8*)(wbf + 65536 + (nt * 16 + l15) * 256 + kk * 32 + quad * 8);
            acc[0][nt] = __builtin_amdgcn_mfma_f32_16x16x32_bf16(zf[0], bfr, acc[0][nt], 0, 0, 0);
            acc[1][nt] = __builtin_amdgcn_mfma_f32_16x16x32_bf16(zf[1], bfr, acc[1][nt], 0, 0, 0);
        }
    }

#pragma unroll
    for (int nt = 0; nt < 16; ++nt) {
        float bov = bo[nt * 16 + l15];
#pragma unroll
        for (int w = 0; w < 2; ++w) {
            float* orow = out + (size_t)(wid0 + w) * 4096;
#pragma unroll
            for (int r = 0; r < 4; ++r)
                orow[(quad * 4 + r) * 256 + nt * 16 + l15] = acc[w][nt][r] + bov;
        }
    }
}

extern "C" void kernel_launch(void* const* d_in, const int* in_sizes, int n_in,
                              void* d_out, int out_size, void* d_ws, size_t ws_size,
                              hipStream_t stream) {
    const float* x  = (const float*)d_in[0];
    const float* Wq = (const float*)d_in[1];
    const float* bq = (const float*)d_in[2];
    const float* Wo = (const float*)d_in[3];
    const float* bo = (const float*)d_in[4];
    float* out = (float*)d_out;
    short* wbf = (short*)d_ws;  // [0,65536): Wq bf16; [65536,131072): Wo bf16

    hipLaunchKernelGGL(convert_weights, dim3(128), dim3(256), 0, stream, Wq, Wo, wbf);
    hipLaunchKernelGGL(lsa_fused, dim3(2048), dim3(256), 0, stream,
                       x, wbf, bq, bo, out);
}